// Round 19
// baseline (757.493 us; speedup 1.0000x reference)
//
#include <hip/hip_runtime.h>

#define DIN 128      // D_IN == N_HEADS*D_HEAD == 128
#define NHEADS 8
#define DHEAD 16
#define EPB 64       // edges per block (fused edge kernel)

typedef __attribute__((ext_vector_type(8))) short short8;   // 8 bf16 (4 VGPRs)
typedef __attribute__((ext_vector_type(4))) float f32x4;    // MFMA C/D + NT ld/st

__device__ __forceinline__ float clip5(float x) {
    return fminf(fmaxf(x, -5.0f), 5.0f);
}

__device__ __forceinline__ unsigned short f2bf(float f) {   // RNE f32->bf16
    unsigned u = __float_as_uint(f);
    unsigned r = (u + 0x7FFF + ((u >> 16) & 1)) >> 16;
    return (unsigned short)r;
}

__device__ __forceinline__ float b2f(unsigned short u) {    // bf16 -> f32
    return __uint_as_float((unsigned)u << 16);
}

// ---------------- all 4 weight matrices -> bf16 transposed [n][k] ----------------

__global__ __launch_bounds__(256) void prep_w_kernel(
    const float* __restrict__ WQ, const float* __restrict__ WK,
    const float* __restrict__ WV, const float* __restrict__ WE,
    unsigned short* __restrict__ Wt) {
    int idx = blockIdx.x * 256 + threadIdx.x;    // 0..65535
    int m = idx >> 14, r = idx & 16383;
    int kk = r >> 7, n = r & 127;
    const float* Ws[4] = {WQ, WK, WV, WE};
    Wt[m * 16384 + n * DIN + kk] = f2bf(Ws[m][kk * DIN + n]);
}

// ---------------- node projections via MFMA (q,k,v -> bf16) ----------------
// 64 nodes/block, 4 waves; lane: lr = node, lg = k/feature group. Same
// operand-swap layout as the edge kernel (A = W features, B = node rows).

__global__ __launch_bounds__(256) void node_mfma_kernel(
    const float* __restrict__ x, const unsigned short* __restrict__ Wt,
    unsigned short* __restrict__ qbf, unsigned short* __restrict__ kbf,
    unsigned short* __restrict__ vbf, int N) {
    const int tid = threadIdx.x;
    const int w = tid >> 6;
    const int l = tid & 63;
    const int lr = l & 15;
    const int lg = l >> 4;
    int n = blockIdx.x * 64 + w * 16 + lr;
    const bool ok = n < N;
    const int nc = ok ? n : N - 1;               // clamped for loads

    const float* xrow = &x[(long)nc * DIN + lg * 8];
    f32x4 xa[8];
#pragma unroll
    for (int ks = 0; ks < 4; ++ks) {
        xa[ks * 2]     = *(const f32x4*)&xrow[ks * 32];
        xa[ks * 2 + 1] = *(const f32x4*)&xrow[ks * 32 + 4];
    }
    short8 bfrag[4];
#pragma unroll
    for (int ks = 0; ks < 4; ++ks) {
        f32x4 a0 = xa[ks * 2], a1 = xa[ks * 2 + 1];
        short8 f;
        f[0] = (short)f2bf(a0[0]); f[1] = (short)f2bf(a0[1]);
        f[2] = (short)f2bf(a0[2]); f[3] = (short)f2bf(a0[3]);
        f[4] = (short)f2bf(a1[0]); f[5] = (short)f2bf(a1[1]);
        f[6] = (short)f2bf(a1[2]); f[7] = (short)f2bf(a1[3]);
        bfrag[ks] = f;
    }

    unsigned short* outs[3] = {qbf, kbf, vbf};
#pragma unroll
    for (int m = 0; m < 3; ++m) {
        const unsigned short* Wm = Wt + m * 16384;
#pragma unroll
        for (int ft = 0; ft < 8; ++ft) {
            f32x4 acc = (f32x4){0.f, 0.f, 0.f, 0.f};
#pragma unroll
            for (int ks = 0; ks < 4; ++ks) {
                short8 af = *(const short8*)&Wm[(ft * 16 + lr) * DIN + ks * 32 + lg * 8];
                acc = __builtin_amdgcn_mfma_f32_16x16x32_bf16(af, bfrag[ks], acc, 0, 0, 0);
            }
            if (ok) {
                ushort4 b;
                b.x = f2bf(acc[0]); b.y = f2bf(acc[1]);
                b.z = f2bf(acc[2]); b.w = f2bf(acc[3]);
                *(ushort4*)&outs[m][(long)n * DIN + ft * 16 + lg * 4] = b;
            }
        }
    }
}

// ---------------- CSR build (counting sort by destination col) ----------------

__global__ __launch_bounds__(256) void degree_kernel(
    const int* __restrict__ cols, int* __restrict__ deg, int E) {
    int e = blockIdx.x * 256 + threadIdx.x;
    if (e < E) atomicAdd(&deg[cols[e]], 1);
}

__global__ __launch_bounds__(256) void block_sum_kernel(
    const int* __restrict__ deg, int* __restrict__ bsum, int N) {
    __shared__ int s[256];
    int tid = threadIdx.x;
    int i = blockIdx.x * 256 + tid;
    s[tid] = (i < N) ? deg[i] : 0;
    __syncthreads();
    for (int st = 128; st > 0; st >>= 1) {
        if (tid < st) s[tid] += s[tid + st];
        __syncthreads();
    }
    if (tid == 0) bsum[blockIdx.x] = s[0];
}

__global__ __launch_bounds__(256) void scan_bsum_kernel(int* __restrict__ bsum, int NB) {
    __shared__ int s[256];
    int tid = threadIdx.x;
    int v = (tid < NB) ? bsum[tid] : 0;
    s[tid] = v;
    __syncthreads();
    for (int off = 1; off < 256; off <<= 1) {
        int t = (tid >= off) ? s[tid - off] : 0;
        __syncthreads();
        s[tid] += t;
        __syncthreads();
    }
    if (tid < NB) bsum[tid] = s[tid] - v;   // exclusive
}

__global__ __launch_bounds__(256) void offsets_kernel(
    const int* __restrict__ deg, const int* __restrict__ bsumscan,
    int* __restrict__ cursor, int N) {
    __shared__ int s[256];
    int tid = threadIdx.x;
    int i = blockIdx.x * 256 + tid;
    int v = (i < N) ? deg[i] : 0;
    s[tid] = v;
    __syncthreads();
    for (int off = 1; off < 256; off <<= 1) {
        int t = (tid >= off) ? s[tid - off] : 0;
        __syncthreads();
        s[tid] += t;
        __syncthreads();
    }
    int excl = s[tid] - v + bsumscan[blockIdx.x];
    if (i < N) cursor[i] = excl;
}

__global__ __launch_bounds__(256) void scatter_kernel(
    const int* __restrict__ rows, const int* __restrict__ cols,
    int* __restrict__ cursor, int* __restrict__ elist,
    int* __restrict__ rows_s, int* __restrict__ cols_s, int E) {
    int e = blockIdx.x * 256 + threadIdx.x;
    if (e >= E) return;
    int c = cols[e];
    int pos = atomicAdd(&cursor[c], 1);
    elist[pos] = e;
    rows_s[pos] = rows[e];
    cols_s[pos] = c;
}

// ---------------- fused edge compute + PV aggregation ----------------
// R13 edge kernel + in-block PV: per-block rank-scan over sorted dests,
// LDS accumulate ax*v into wacc[rank][feat] (ds_add_f32), one global
// atomicAdd per (dest,feat) at flush (~6 dests/block). Deletes the
// separate aggregate pass (its 2.4M v-row lines move here; ax round-trip
// and rows_s second read disappear).

__global__ __launch_bounds__(256) void edge_fused_kernel(
    const float* __restrict__ edge_attr, const int* __restrict__ elist,
    const int* __restrict__ rows_s, const int* __restrict__ cols_s,
    const unsigned short* __restrict__ WEt, const unsigned short* __restrict__ qbf,
    const unsigned short* __restrict__ kbf, const unsigned short* __restrict__ vbf,
    float* __restrict__ e_out, float* __restrict__ wV, float* __restrict__ z,
    int E) {
    __shared__ float wacc[EPB][DIN + 4];     // +4 pad: breaks 32-bank stride
    __shared__ float zacc[EPB][NHEADS];
    __shared__ int rank_s[EPB];
    __shared__ int dest_s[EPB];
    __shared__ int nranks_s;

    const int tid = threadIdx.x;
    const int e0 = blockIdx.x * EPB;              // E % EPB == 0
    const int w = tid >> 6;
    const int l = tid & 63;
    const int lr = l & 15;
    const int lg = l >> 4;
    const int j = e0 + w * 16 + lr;  // sorted position

    // zero accumulators
    for (int i = tid; i < EPB * (DIN + 4); i += 256)
        ((float*)wacc)[i] = 0.f;
    for (int i = tid; i < EPB * NHEADS; i += 256)
        ((float*)zacc)[i] = 0.f;

    // rank scan (wave 0): rank = distinct-dest index within block
    if (tid < EPB) {
        int c = cols_s[e0 + tid];
        int cp = (tid == 0) ? -1 : cols_s[e0 + tid - 1];
        int b = (c != cp) ? 1 : 0;
        int s = b;
#pragma unroll
        for (int off = 1; off < EPB; off <<= 1) {
            int t = __shfl_up(s, off);
            if (tid >= off) s += t;
        }
        rank_s[tid] = s - 1;
        if (b) dest_s[s - 1] = c;
        if (tid == EPB - 1) nranks_s = s;
    }

    const long eg = elist[j];
    const int er = rows_s[j];
    const int ec = cols_s[j];

    // ---- burst: 8 edge_attr NT loads + 24 k/q/v gathers ----
    const float* arow = &edge_attr[eg * DIN + lg * 8];
    f32x4 ea[8];
#pragma unroll
    for (int ks = 0; ks < 4; ++ks) {
        ea[ks * 2]     = __builtin_nontemporal_load((const f32x4*)&arow[ks * 32]);
        ea[ks * 2 + 1] = __builtin_nontemporal_load((const f32x4*)&arow[ks * 32 + 4]);
    }
    const unsigned short* krow = &kbf[(long)er * DIN + lg * 4];
    const unsigned short* qrow = &qbf[(long)ec * DIN + lg * 4];
    const unsigned short* vrow = &vbf[(long)er * DIN + lg * 4];
    ushort4 kv[8], qv[8], vv[8];
#pragma unroll
    for (int ft = 0; ft < 8; ++ft) {
        kv[ft] = *(const ushort4*)&krow[ft * 16];
        qv[ft] = *(const ushort4*)&qrow[ft * 16];
        vv[ft] = *(const ushort4*)&vrow[ft * 16];
    }
    __builtin_amdgcn_sched_barrier(0);   // loads stay a burst

    short8 bfrag[4];
#pragma unroll
    for (int ks = 0; ks < 4; ++ks) {
        f32x4 a0 = ea[ks * 2], a1 = ea[ks * 2 + 1];
        short8 f;
        f[0] = (short)f2bf(a0[0]); f[1] = (short)f2bf(a0[1]);
        f[2] = (short)f2bf(a0[2]); f[3] = (short)f2bf(a0[3]);
        f[4] = (short)f2bf(a1[0]); f[5] = (short)f2bf(a1[1]);
        f[6] = (short)f2bf(a1[2]); f[7] = (short)f2bf(a1[3]);
        bfrag[ks] = f;
    }

    __syncthreads();                     // rank_s/dest_s + zeroed acc ready
    const int myrank = rank_s[w * 16 + lr];

#pragma unroll
    for (int ft = 0; ft < 8; ++ft) {             // ft == head
        f32x4 acc = (f32x4){0.f, 0.f, 0.f, 0.f};
#pragma unroll
        for (int ks = 0; ks < 4; ++ks) {
            short8 af = *(const short8*)&WEt[(ft * 16 + lr) * DIN + ks * 32 + lg * 8];
            acc = __builtin_amdgcn_mfma_f32_16x16x32_bf16(af, bfrag[ks], acc, 0, 0, 0);
        }
        const int f0 = ft * 16 + lg * 4;         // 4 consecutive features
        f32x4 t;
        t[0] = clip5(b2f(kv[ft].x) * b2f(qv[ft].x) * 0.25f) * acc[0];
        t[1] = clip5(b2f(kv[ft].y) * b2f(qv[ft].y) * 0.25f) * acc[1];
        t[2] = clip5(b2f(kv[ft].z) * b2f(qv[ft].z) * 0.25f) * acc[2];
        t[3] = clip5(b2f(kv[ft].w) * b2f(qv[ft].w) * 0.25f) * acc[3];
        __builtin_nontemporal_store(t, (f32x4*)&e_out[eg * DIN + f0]);

        float s = t[0] + t[1] + t[2] + t[3];
        s += __shfl_xor(s, 16);                  // head-sum over lg groups
        s += __shfl_xor(s, 32);
        float axv = __expf(clip5(s));

        // PV accumulate: ax * v into this edge's rank slot
        atomicAdd(&wacc[myrank][f0 + 0], axv * b2f(vv[ft].x));
        atomicAdd(&wacc[myrank][f0 + 1], axv * b2f(vv[ft].y));
        atomicAdd(&wacc[myrank][f0 + 2], axv * b2f(vv[ft].z));
        atomicAdd(&wacc[myrank][f0 + 3], axv * b2f(vv[ft].w));
        if (lg == 0) atomicAdd(&zacc[myrank][ft], axv);
    }

    __syncthreads();
    const int nr = nranks_s;
    // flush wacc: 2 rank-rows per 256 threads
    for (int base = 0; base < nr; base += 2) {
        int r = base + (tid >> 7);
        int f = tid & 127;
        if (r < nr) {
            float val = wacc[r][f];
            if (val != 0.f) atomicAdd(&wV[(long)dest_s[r] * DIN + f], val);
        }
    }
    if (tid < EPB * NHEADS) {
        int r = tid >> 3, h = tid & 7;
        if (r < nr) {
            float val = zacc[r][h];
            if (val != 0.f) atomicAdd(&z[(long)dest_s[r] * NHEADS + h], val);
        }
    }
}

// ---------------- normalize: h = wV / (z + 1e-6) ----------------

__global__ __launch_bounds__(256) void normalize_kernel(
    float* __restrict__ h, const float* __restrict__ z, int N) {
    long idx = (long)blockIdx.x * 256 + threadIdx.x;   // one f32x4 each
    if (idx >= (long)N * 32) return;
    int n = (int)(idx >> 5);
    int fq = (int)(idx & 31);
    float inv = 1.0f / (z[n * NHEADS + (fq >> 2)] + 1e-6f);
    f32x4 v = *(f32x4*)&h[(long)n * DIN + fq * 4];
    v[0] *= inv; v[1] *= inv; v[2] *= inv; v[3] *= inv;
    *(f32x4*)&h[(long)n * DIN + fq * 4] = v;
}

extern "C" void kernel_launch(void* const* d_in, const int* in_sizes, int n_in,
                              void* d_out, int out_size, void* d_ws, size_t ws_size,
                              hipStream_t stream) {
    const float* x         = (const float*)d_in[0];
    const float* edge_attr = (const float*)d_in[1];
    const int*   edge_index= (const int*)d_in[2];
    const float* WQ        = (const float*)d_in[3];
    const float* WK        = (const float*)d_in[4];
    const float* WV        = (const float*)d_in[5];
    const float* WE        = (const float*)d_in[6];

    const int N = in_sizes[0] / DIN;     // 50000
    const int E = in_sizes[2] / 2;       // 600000 (multiple of 64)
    const int NB = (N + 255) / 256;

    float* out   = (float*)d_out;
    float* h_out = out;                        // [N,128] — atomic accum + normalize
    float* e_out = out + (long)N * DIN;        // [E,128]

    unsigned short* qbf = (unsigned short*)d_ws;            // [N,128] bf16
    unsigned short* kbf = qbf + (long)N * DIN;              // [N,128] bf16
    unsigned short* vbf = kbf + (long)N * DIN;              // [N,128] bf16
    float* z = (float*)(vbf + (long)N * DIN);               // [N,8]
    unsigned short* Wt = (unsigned short*)(z + (long)N * NHEADS);  // 4x[128,128] bf16
    int* ip      = (int*)(Wt + 4 * 16384);
    int* deg     = ip;                         // [N]
    int* cursor  = deg + N;                    // [N]
    int* bsum    = cursor + N;                 // [NB]
    int* elist   = bsum + 256;                 // [E]
    int* rows_s  = elist + E;                  // [E]
    int* cols_s  = rows_s + E;                 // [E]

    const int* rows = edge_index;
    const int* cols = edge_index + E;

    hipMemsetAsync(deg, 0, (size_t)N * sizeof(int), stream);
    hipMemsetAsync(z, 0, (size_t)N * NHEADS * sizeof(float), stream);
    hipMemsetAsync(h_out, 0, (size_t)N * DIN * sizeof(float), stream);

    prep_w_kernel<<<4 * 16384 / 256, 256, 0, stream>>>(WQ, WK, WV, WE, Wt);
    node_mfma_kernel<<<(N + 63) / 64, 256, 0, stream>>>(x, Wt, qbf, kbf, vbf, N);

    degree_kernel<<<(E + 255) / 256, 256, 0, stream>>>(cols, deg, E);
    block_sum_kernel<<<NB, 256, 0, stream>>>(deg, bsum, N);
    scan_bsum_kernel<<<1, 256, 0, stream>>>(bsum, NB);
    offsets_kernel<<<NB, 256, 0, stream>>>(deg, bsum, cursor, N);
    scatter_kernel<<<(E + 255) / 256, 256, 0, stream>>>(rows, cols, cursor,
                                                        elist, rows_s, cols_s, E);

    edge_fused_kernel<<<E / EPB, 256, 0, stream>>>(
        edge_attr, elist, rows_s, cols_s, Wt + 3 * 16384, qbf, kbf, vbf,
        e_out, h_out, z, E);

    normalize_kernel<<<(int)(((long)N * 32 + 255) / 256), 256, 0, stream>>>(h_out, z, N);
}

// Round 20
// 492.476 us; speedup vs baseline: 1.5381x; 1.5381x over previous
//
#include <hip/hip_runtime.h>

#define DIN 128      // D_IN == N_HEADS*D_HEAD == 128
#define NHEADS 8
#define DHEAD 16
#define EPB 64       // edges per block (fused edge kernel)

typedef __attribute__((ext_vector_type(8))) short short8;   // 8 bf16 (4 VGPRs)
typedef __attribute__((ext_vector_type(4))) float f32x4;    // MFMA C/D + NT ld/st

__device__ __forceinline__ float clip5(float x) {
    return fminf(fmaxf(x, -5.0f), 5.0f);
}

__device__ __forceinline__ unsigned short f2bf(float f) {   // RNE f32->bf16
    unsigned u = __float_as_uint(f);
    unsigned r = (u + 0x7FFF + ((u >> 16) & 1)) >> 16;
    return (unsigned short)r;
}

__device__ __forceinline__ float b2f(unsigned short u) {    // bf16 -> f32
    return __uint_as_float((unsigned)u << 16);
}

// ---------------- all 4 weight matrices -> bf16 transposed [n][k] ----------------

__global__ __launch_bounds__(256) void prep_w_kernel(
    const float* __restrict__ WQ, const float* __restrict__ WK,
    const float* __restrict__ WV, const float* __restrict__ WE,
    unsigned short* __restrict__ Wt) {
    int idx = blockIdx.x * 256 + threadIdx.x;    // 0..65535
    int m = idx >> 14, r = idx & 16383;
    int kk = r >> 7, n = r & 127;
    const float* Ws[4] = {WQ, WK, WV, WE};
    Wt[m * 16384 + n * DIN + kk] = f2bf(Ws[m][kk * DIN + n]);
}

// ---------------- node projections via MFMA (q,k,v -> bf16) ----------------

__global__ __launch_bounds__(256) void node_mfma_kernel(
    const float* __restrict__ x, const unsigned short* __restrict__ Wt,
    unsigned short* __restrict__ qbf, unsigned short* __restrict__ kbf,
    unsigned short* __restrict__ vbf, int N) {
    const int tid = threadIdx.x;
    const int w = tid >> 6;
    const int l = tid & 63;
    const int lr = l & 15;
    const int lg = l >> 4;
    int n = blockIdx.x * 64 + w * 16 + lr;
    const bool ok = n < N;
    const int nc = ok ? n : N - 1;               // clamped for loads

    const float* xrow = &x[(long)nc * DIN + lg * 8];
    f32x4 xa[8];
#pragma unroll
    for (int ks = 0; ks < 4; ++ks) {
        xa[ks * 2]     = *(const f32x4*)&xrow[ks * 32];
        xa[ks * 2 + 1] = *(const f32x4*)&xrow[ks * 32 + 4];
    }
    short8 bfrag[4];
#pragma unroll
    for (int ks = 0; ks < 4; ++ks) {
        f32x4 a0 = xa[ks * 2], a1 = xa[ks * 2 + 1];
        short8 f;
        f[0] = (short)f2bf(a0[0]); f[1] = (short)f2bf(a0[1]);
        f[2] = (short)f2bf(a0[2]); f[3] = (short)f2bf(a0[3]);
        f[4] = (short)f2bf(a1[0]); f[5] = (short)f2bf(a1[1]);
        f[6] = (short)f2bf(a1[2]); f[7] = (short)f2bf(a1[3]);
        bfrag[ks] = f;
    }

    unsigned short* outs[3] = {qbf, kbf, vbf};
#pragma unroll
    for (int m = 0; m < 3; ++m) {
        const unsigned short* Wm = Wt + m * 16384;
#pragma unroll
        for (int ft = 0; ft < 8; ++ft) {
            f32x4 acc = (f32x4){0.f, 0.f, 0.f, 0.f};
#pragma unroll
            for (int ks = 0; ks < 4; ++ks) {
                short8 af = *(const short8*)&Wm[(ft * 16 + lr) * DIN + ks * 32 + lg * 8];
                acc = __builtin_amdgcn_mfma_f32_16x16x32_bf16(af, bfrag[ks], acc, 0, 0, 0);
            }
            if (ok) {
                ushort4 b;
                b.x = f2bf(acc[0]); b.y = f2bf(acc[1]);
                b.z = f2bf(acc[2]); b.w = f2bf(acc[3]);
                *(ushort4*)&outs[m][(long)n * DIN + ft * 16 + lg * 4] = b;
            }
        }
    }
}

// ---------------- CSR build (counting sort by destination col) ----------------

__global__ __launch_bounds__(256) void degree_kernel(
    const int* __restrict__ cols, int* __restrict__ deg, int E) {
    int e = blockIdx.x * 256 + threadIdx.x;
    if (e < E) atomicAdd(&deg[cols[e]], 1);
}

__global__ __launch_bounds__(256) void block_sum_kernel(
    const int* __restrict__ deg, int* __restrict__ bsum, int N) {
    __shared__ int s[256];
    int tid = threadIdx.x;
    int i = blockIdx.x * 256 + tid;
    s[tid] = (i < N) ? deg[i] : 0;
    __syncthreads();
    for (int st = 128; st > 0; st >>= 1) {
        if (tid < st) s[tid] += s[tid + st];
        __syncthreads();
    }
    if (tid == 0) bsum[blockIdx.x] = s[0];
}

__global__ __launch_bounds__(256) void scan_bsum_kernel(int* __restrict__ bsum, int NB) {
    __shared__ int s[256];
    int tid = threadIdx.x;
    int v = (tid < NB) ? bsum[tid] : 0;
    s[tid] = v;
    __syncthreads();
    for (int off = 1; off < 256; off <<= 1) {
        int t = (tid >= off) ? s[tid - off] : 0;
        __syncthreads();
        s[tid] += t;
        __syncthreads();
    }
    if (tid < NB) bsum[tid] = s[tid] - v;   // exclusive
}

__global__ __launch_bounds__(256) void offsets_kernel(
    const int* __restrict__ deg, const int* __restrict__ bsumscan,
    int* __restrict__ cursor, int N) {
    __shared__ int s[256];
    int tid = threadIdx.x;
    int i = blockIdx.x * 256 + tid;
    int v = (i < N) ? deg[i] : 0;
    s[tid] = v;
    __syncthreads();
    for (int off = 1; off < 256; off <<= 1) {
        int t = (tid >= off) ? s[tid - off] : 0;
        __syncthreads();
        s[tid] += t;
        __syncthreads();
    }
    int excl = s[tid] - v + bsumscan[blockIdx.x];
    if (i < N) cursor[i] = excl;
}

__global__ __launch_bounds__(256) void scatter_kernel(
    const int* __restrict__ rows, const int* __restrict__ cols,
    int* __restrict__ cursor, int* __restrict__ elist,
    int* __restrict__ rows_s, int* __restrict__ cols_s, int E) {
    int e = blockIdx.x * 256 + threadIdx.x;
    if (e >= E) return;
    int c = cols[e];
    int pos = atomicAdd(&cursor[c], 1);
    elist[pos] = e;
    rows_s[pos] = rows[e];
    cols_s[pos] = c;
}

// ---------------- fused edge compute + PV aggregation ----------------
// R13 edge kernel + v[er] riding the k[er] gather burst. PV accumulation
// via SEGMENTED SHUFFLE SCAN over the sorted 16-lane window (edges sharing
// a dest are contiguous) -> only segment-tail lanes (~2.3/window, vs 16)
// issue global atomicAdds. No LDS, no barriers (R19's LDS-atomic storm
// serialized ~12-way on shared ranks: 619us; this removes it).

__global__ __launch_bounds__(256) void edge_fused_kernel(
    const float* __restrict__ edge_attr, const int* __restrict__ elist,
    const int* __restrict__ rows_s, const int* __restrict__ cols_s,
    const unsigned short* __restrict__ WEt, const unsigned short* __restrict__ qbf,
    const unsigned short* __restrict__ kbf, const unsigned short* __restrict__ vbf,
    float* __restrict__ e_out, float* __restrict__ wV, float* __restrict__ z,
    int E) {
    const int tid = threadIdx.x;
    const int e0 = blockIdx.x * EPB;              // E % EPB == 0
    const int w = tid >> 6;
    const int l = tid & 63;
    const int lr = l & 15;
    const int lg = l >> 4;
    const int j = e0 + w * 16 + lr;  // sorted position

    const long eg = elist[j];
    const int er = rows_s[j];
    const int ec = cols_s[j];        // sorted: equal dests contiguous in window

    // ---- burst: 8 edge_attr NT loads + 24 k/q/v gathers ----
    const float* arow = &edge_attr[eg * DIN + lg * 8];
    f32x4 ea[8];
#pragma unroll
    for (int ks = 0; ks < 4; ++ks) {
        ea[ks * 2]     = __builtin_nontemporal_load((const f32x4*)&arow[ks * 32]);
        ea[ks * 2 + 1] = __builtin_nontemporal_load((const f32x4*)&arow[ks * 32 + 4]);
    }
    const unsigned short* krow = &kbf[(long)er * DIN + lg * 4];
    const unsigned short* qrow = &qbf[(long)ec * DIN + lg * 4];
    const unsigned short* vrow = &vbf[(long)er * DIN + lg * 4];
    ushort4 kv[8], qv[8], vv[8];
#pragma unroll
    for (int ft = 0; ft < 8; ++ft) {
        kv[ft] = *(const ushort4*)&krow[ft * 16];
        qv[ft] = *(const ushort4*)&qrow[ft * 16];
        vv[ft] = *(const ushort4*)&vrow[ft * 16];
    }
    __builtin_amdgcn_sched_barrier(0);   // loads stay a burst

    short8 bfrag[4];
#pragma unroll
    for (int ks = 0; ks < 4; ++ks) {
        f32x4 a0 = ea[ks * 2], a1 = ea[ks * 2 + 1];
        short8 f;
        f[0] = (short)f2bf(a0[0]); f[1] = (short)f2bf(a0[1]);
        f[2] = (short)f2bf(a0[2]); f[3] = (short)f2bf(a0[3]);
        f[4] = (short)f2bf(a1[0]); f[5] = (short)f2bf(a1[1]);
        f[6] = (short)f2bf(a1[2]); f[7] = (short)f2bf(a1[3]);
        bfrag[ks] = f;
    }

    // segment predicates from neighbor-ec compares (hoisted out of ft loop)
    const int ec1 = __shfl_up(ec, 1, 16);
    const int ec2 = __shfl_up(ec, 2, 16);
    const int ec4 = __shfl_up(ec, 4, 16);
    const int ec8 = __shfl_up(ec, 8, 16);
    const int ecn = __shfl_down(ec, 1, 16);
    const bool take1 = (lr >= 1) && (ec1 == ec);
    const bool take2 = (lr >= 2) && (ec2 == ec);
    const bool take4 = (lr >= 4) && (ec4 == ec);
    const bool take8 = (lr >= 8) && (ec8 == ec);
    const bool tail  = (lr == 15) || (ecn != ec);

#pragma unroll
    for (int ft = 0; ft < 8; ++ft) {             // ft == head
        f32x4 acc = (f32x4){0.f, 0.f, 0.f, 0.f};
#pragma unroll
        for (int ks = 0; ks < 4; ++ks) {
            short8 af = *(const short8*)&WEt[(ft * 16 + lr) * DIN + ks * 32 + lg * 8];
            acc = __builtin_amdgcn_mfma_f32_16x16x32_bf16(af, bfrag[ks], acc, 0, 0, 0);
        }
        const int f0 = ft * 16 + lg * 4;         // 4 consecutive features
        f32x4 t;
        t[0] = clip5(b2f(kv[ft].x) * b2f(qv[ft].x) * 0.25f) * acc[0];
        t[1] = clip5(b2f(kv[ft].y) * b2f(qv[ft].y) * 0.25f) * acc[1];
        t[2] = clip5(b2f(kv[ft].z) * b2f(qv[ft].z) * 0.25f) * acc[2];
        t[3] = clip5(b2f(kv[ft].w) * b2f(qv[ft].w) * 0.25f) * acc[3];
        __builtin_nontemporal_store(t, (f32x4*)&e_out[eg * DIN + f0]);

        float s = t[0] + t[1] + t[2] + t[3];
        s += __shfl_xor(s, 16);                  // head-sum over lg groups
        s += __shfl_xor(s, 32);                  // (all 64 lanes get full sum)
        float axv = __expf(clip5(s));

        // pv = ax * v (this lane's 4 features); segmented inclusive scan
        float p0 = axv * b2f(vv[ft].x);
        float p1 = axv * b2f(vv[ft].y);
        float p2 = axv * b2f(vv[ft].z);
        float p3 = axv * b2f(vv[ft].w);
        float zl = axv;

        {
            float u0 = __shfl_up(p0, 1, 16), u1 = __shfl_up(p1, 1, 16);
            float u2 = __shfl_up(p2, 1, 16), u3 = __shfl_up(p3, 1, 16);
            float uz = __shfl_up(zl, 1, 16);
            if (take1) { p0 += u0; p1 += u1; p2 += u2; p3 += u3; zl += uz; }
        }
        {
            float u0 = __shfl_up(p0, 2, 16), u1 = __shfl_up(p1, 2, 16);
            float u2 = __shfl_up(p2, 2, 16), u3 = __shfl_up(p3, 2, 16);
            float uz = __shfl_up(zl, 2, 16);
            if (take2) { p0 += u0; p1 += u1; p2 += u2; p3 += u3; zl += uz; }
        }
        {
            float u0 = __shfl_up(p0, 4, 16), u1 = __shfl_up(p1, 4, 16);
            float u2 = __shfl_up(p2, 4, 16), u3 = __shfl_up(p3, 4, 16);
            float uz = __shfl_up(zl, 4, 16);
            if (take4) { p0 += u0; p1 += u1; p2 += u2; p3 += u3; zl += uz; }
        }
        {
            float u0 = __shfl_up(p0, 8, 16), u1 = __shfl_up(p1, 8, 16);
            float u2 = __shfl_up(p2, 8, 16), u3 = __shfl_up(p3, 8, 16);
            float uz = __shfl_up(zl, 8, 16);
            if (take8) { p0 += u0; p1 += u1; p2 += u2; p3 += u3; zl += uz; }
        }

        if (tail) {                              // one atomic set per segment
            float* wp = &wV[(long)ec * DIN + f0];
            atomicAdd(wp + 0, p0);
            atomicAdd(wp + 1, p1);
            atomicAdd(wp + 2, p2);
            atomicAdd(wp + 3, p3);
            if (lg == 0) atomicAdd(&z[(long)ec * NHEADS + ft], zl);
        }
    }
}

// ---------------- normalize: h = wV / (z + 1e-6) ----------------

__global__ __launch_bounds__(256) void normalize_kernel(
    float* __restrict__ h, const float* __restrict__ z, int N) {
    long idx = (long)blockIdx.x * 256 + threadIdx.x;   // one f32x4 each
    if (idx >= (long)N * 32) return;
    int n = (int)(idx >> 5);
    int fq = (int)(idx & 31);
    float inv = 1.0f / (z[n * NHEADS + (fq >> 2)] + 1e-6f);
    f32x4 v = *(f32x4*)&h[(long)n * DIN + fq * 4];
    v[0] *= inv; v[1] *= inv; v[2] *= inv; v[3] *= inv;
    *(f32x4*)&h[(long)n * DIN + fq * 4] = v;
}

extern "C" void kernel_launch(void* const* d_in, const int* in_sizes, int n_in,
                              void* d_out, int out_size, void* d_ws, size_t ws_size,
                              hipStream_t stream) {
    const float* x         = (const float*)d_in[0];
    const float* edge_attr = (const float*)d_in[1];
    const int*   edge_index= (const int*)d_in[2];
    const float* WQ        = (const float*)d_in[3];
    const float* WK        = (const float*)d_in[4];
    const float* WV        = (const float*)d_in[5];
    const float* WE        = (const float*)d_in[6];

    const int N = in_sizes[0] / DIN;     // 50000
    const int E = in_sizes[2] / 2;       // 600000 (multiple of 64)
    const int NB = (N + 255) / 256;

    float* out   = (float*)d_out;
    float* h_out = out;                        // [N,128] — atomic accum + normalize
    float* e_out = out + (long)N * DIN;        // [E,128]

    unsigned short* qbf = (unsigned short*)d_ws;            // [N,128] bf16
    unsigned short* kbf = qbf + (long)N * DIN;              // [N,128] bf16
    unsigned short* vbf = kbf + (long)N * DIN;              // [N,128] bf16
    float* z = (float*)(vbf + (long)N * DIN);               // [N,8]
    unsigned short* Wt = (unsigned short*)(z + (long)N * NHEADS);  // 4x[128,128] bf16
    int* ip      = (int*)(Wt + 4 * 16384);
    int* deg     = ip;                         // [N]
    int* cursor  = deg + N;                    // [N]
    int* bsum    = cursor + N;                 // [NB]
    int* elist   = bsum + 256;                 // [E]
    int* rows_s  = elist + E;                  // [E]
    int* cols_s  = rows_s + E;                 // [E]

    const int* rows = edge_index;
    const int* cols = edge_index + E;

    hipMemsetAsync(deg, 0, (size_t)N * sizeof(int), stream);
    hipMemsetAsync(z, 0, (size_t)N * NHEADS * sizeof(float), stream);
    hipMemsetAsync(h_out, 0, (size_t)N * DIN * sizeof(float), stream);

    prep_w_kernel<<<4 * 16384 / 256, 256, 0, stream>>>(WQ, WK, WV, WE, Wt);
    node_mfma_kernel<<<(N + 63) / 64, 256, 0, stream>>>(x, Wt, qbf, kbf, vbf, N);

    degree_kernel<<<(E + 255) / 256, 256, 0, stream>>>(cols, deg, E);
    block_sum_kernel<<<NB, 256, 0, stream>>>(deg, bsum, N);
    scan_bsum_kernel<<<1, 256, 0, stream>>>(bsum, NB);
    offsets_kernel<<<NB, 256, 0, stream>>>(deg, bsum, cursor, N);
    scatter_kernel<<<(E + 255) / 256, 256, 0, stream>>>(rows, cols, cursor,
                                                        elist, rows_s, cols_s, E);

    edge_fused_kernel<<<E / EPB, 256, 0, stream>>>(
        edge_attr, elist, rows_s, cols_s, Wt + 3 * 16384, qbf, kbf, vbf,
        e_out, h_out, z, E);

    normalize_kernel<<<(int)(((long)N * 32 + 255) / 256), 256, 0, stream>>>(h_out, z, N);
}

// Round 21
// 443.474 us; speedup vs baseline: 1.7081x; 1.1105x over previous
//
#include <hip/hip_runtime.h>

#define DIN 128      // D_IN == N_HEADS*D_HEAD == 128
#define NHEADS 8
#define DHEAD 16
#define EPB 64       // edges per block (edge mfma kernel)

typedef __attribute__((ext_vector_type(8))) short short8;   // 8 bf16 (4 VGPRs)
typedef __attribute__((ext_vector_type(4))) float f32x4;    // MFMA C/D + NT ld/st

__device__ __forceinline__ float clip5(float x) {
    return fminf(fmaxf(x, -5.0f), 5.0f);
}

__device__ __forceinline__ unsigned short f2bf(float f) {   // RNE f32->bf16
    unsigned u = __float_as_uint(f);
    unsigned r = (u + 0x7FFF + ((u >> 16) & 1)) >> 16;
    return (unsigned short)r;
}

__device__ __forceinline__ float b2f(unsigned short u) {    // bf16 -> f32
    return __uint_as_float((unsigned)u << 16);
}

__device__ __forceinline__ float bflo(unsigned u) {  // low bf16 of dword
    return __uint_as_float(u << 16);
}
__device__ __forceinline__ float bfhi(unsigned u) {  // high bf16 of dword
    return __uint_as_float(u & 0xffff0000u);
}

// ---------------- all 4 weight matrices -> bf16 transposed [n][k] ----------------

__global__ __launch_bounds__(256) void prep_w_kernel(
    const float* __restrict__ WQ, const float* __restrict__ WK,
    const float* __restrict__ WV, const float* __restrict__ WE,
    unsigned short* __restrict__ Wt) {
    int idx = blockIdx.x * 256 + threadIdx.x;    // 0..65535
    int m = idx >> 14, r = idx & 16383;
    int kk = r >> 7, n = r & 127;
    const float* Ws[4] = {WQ, WK, WV, WE};
    Wt[m * 16384 + n * DIN + kk] = f2bf(Ws[m][kk * DIN + n]);
}

// ---------------- node projections via MFMA (q,k,v -> bf16) ----------------
// 64 nodes/block, 4 waves; lane: lr = node, lg = k/feature group. Validated
// R20 (absmax 0.0625 unchanged); replaces fp32-VALU node_proj (~45us saved).

__global__ __launch_bounds__(256) void node_mfma_kernel(
    const float* __restrict__ x, const unsigned short* __restrict__ Wt,
    unsigned short* __restrict__ qbf, unsigned short* __restrict__ kbf,
    unsigned short* __restrict__ vbf, int N) {
    const int tid = threadIdx.x;
    const int w = tid >> 6;
    const int l = tid & 63;
    const int lr = l & 15;
    const int lg = l >> 4;
    int n = blockIdx.x * 64 + w * 16 + lr;
    const bool ok = n < N;
    const int nc = ok ? n : N - 1;               // clamped for loads

    const float* xrow = &x[(long)nc * DIN + lg * 8];
    f32x4 xa[8];
#pragma unroll
    for (int ks = 0; ks < 4; ++ks) {
        xa[ks * 2]     = *(const f32x4*)&xrow[ks * 32];
        xa[ks * 2 + 1] = *(const f32x4*)&xrow[ks * 32 + 4];
    }
    short8 bfrag[4];
#pragma unroll
    for (int ks = 0; ks < 4; ++ks) {
        f32x4 a0 = xa[ks * 2], a1 = xa[ks * 2 + 1];
        short8 f;
        f[0] = (short)f2bf(a0[0]); f[1] = (short)f2bf(a0[1]);
        f[2] = (short)f2bf(a0[2]); f[3] = (short)f2bf(a0[3]);
        f[4] = (short)f2bf(a1[0]); f[5] = (short)f2bf(a1[1]);
        f[6] = (short)f2bf(a1[2]); f[7] = (short)f2bf(a1[3]);
        bfrag[ks] = f;
    }

    unsigned short* outs[3] = {qbf, kbf, vbf};
#pragma unroll
    for (int m = 0; m < 3; ++m) {
        const unsigned short* Wm = Wt + m * 16384;
#pragma unroll
        for (int ft = 0; ft < 8; ++ft) {
            f32x4 acc = (f32x4){0.f, 0.f, 0.f, 0.f};
#pragma unroll
            for (int ks = 0; ks < 4; ++ks) {
                short8 af = *(const short8*)&Wm[(ft * 16 + lr) * DIN + ks * 32 + lg * 8];
                acc = __builtin_amdgcn_mfma_f32_16x16x32_bf16(af, bfrag[ks], acc, 0, 0, 0);
            }
            if (ok) {
                ushort4 b;
                b.x = f2bf(acc[0]); b.y = f2bf(acc[1]);
                b.z = f2bf(acc[2]); b.w = f2bf(acc[3]);
                *(ushort4*)&outs[m][(long)n * DIN + ft * 16 + lg * 4] = b;
            }
        }
    }
}

// ---------------- CSR build (counting sort by destination col) ----------------

__global__ __launch_bounds__(256) void degree_kernel(
    const int* __restrict__ cols, int* __restrict__ deg, int E) {
    int e = blockIdx.x * 256 + threadIdx.x;
    if (e < E) atomicAdd(&deg[cols[e]], 1);
}

__global__ __launch_bounds__(256) void block_sum_kernel(
    const int* __restrict__ deg, int* __restrict__ bsum, int N) {
    __shared__ int s[256];
    int tid = threadIdx.x;
    int i = blockIdx.x * 256 + tid;
    s[tid] = (i < N) ? deg[i] : 0;
    __syncthreads();
    for (int st = 128; st > 0; st >>= 1) {
        if (tid < st) s[tid] += s[tid + st];
        __syncthreads();
    }
    if (tid == 0) bsum[blockIdx.x] = s[0];
}

__global__ __launch_bounds__(256) void scan_bsum_kernel(int* __restrict__ bsum, int NB) {
    __shared__ int s[256];
    int tid = threadIdx.x;
    int v = (tid < NB) ? bsum[tid] : 0;
    s[tid] = v;
    __syncthreads();
    for (int off = 1; off < 256; off <<= 1) {
        int t = (tid >= off) ? s[tid - off] : 0;
        __syncthreads();
        s[tid] += t;
        __syncthreads();
    }
    if (tid < NB) bsum[tid] = s[tid] - v;   // exclusive
}

__global__ __launch_bounds__(256) void offsets_kernel(
    const int* __restrict__ deg, const int* __restrict__ bsumscan,
    int* __restrict__ offsets, int* __restrict__ cursor, int N, int E) {
    __shared__ int s[256];
    int tid = threadIdx.x;
    int i = blockIdx.x * 256 + tid;
    int v = (i < N) ? deg[i] : 0;
    s[tid] = v;
    __syncthreads();
    for (int off = 1; off < 256; off <<= 1) {
        int t = (tid >= off) ? s[tid - off] : 0;
        __syncthreads();
        s[tid] += t;
        __syncthreads();
    }
    int excl = s[tid] - v + bsumscan[blockIdx.x];
    if (i < N) { offsets[i] = excl; cursor[i] = excl; }
    if (blockIdx.x == 0 && tid == 0) offsets[N] = E;
}

__global__ __launch_bounds__(256) void scatter_kernel(
    const int* __restrict__ rows, const int* __restrict__ cols,
    int* __restrict__ cursor, int* __restrict__ elist,
    int* __restrict__ rows_s, int* __restrict__ cols_s, int E) {
    int e = blockIdx.x * 256 + threadIdx.x;
    if (e >= E) return;
    int c = cols[e];
    int pos = atomicAdd(&cursor[c], 1);
    elist[pos] = e;
    rows_s[pos] = rows[e];
    cols_s[pos] = c;
}

// ---------------- edge compute: MFMA e_proj + e_out + ax_s ----------------
// R13 form (best measured: 285us, VGPR 52, 3x reproduced). Sorted order,
// burst loads, nontemporal one-touch streams. R17 pipeline and R19/R20
// fusion variants both measured worse -> this is the edge endpoint.

__global__ __launch_bounds__(256) void edge_mfma_kernel(
    const float* __restrict__ edge_attr, const int* __restrict__ elist,
    const int* __restrict__ rows_s, const int* __restrict__ cols_s,
    const unsigned short* __restrict__ WEt, const unsigned short* __restrict__ qbf,
    const unsigned short* __restrict__ kbf, float* __restrict__ e_out,
    float* __restrict__ ax_s, int E) {
    const int tid = threadIdx.x;
    const int e0 = blockIdx.x * EPB;              // E % EPB == 0
    const int w = tid >> 6;          // wave 0..3: sorted slots w*16..w*16+15
    const int l = tid & 63;
    const int lr = l & 15;
    const int lg = l >> 4;
    const int j = e0 + w * 16 + lr;  // sorted position
    const long eg = elist[j];        // original edge id (row gather target)
    const int er = rows_s[j];        // contiguous
    const int ec = cols_s[j];        // contiguous, sorted (locality!)

    // ---- burst 1: 8 edge_attr f32x4 loads (own row, nontemporal) ----
    const float* arow = &edge_attr[eg * DIN + lg * 8];
    f32x4 ea[8];
#pragma unroll
    for (int ks = 0; ks < 4; ++ks) {
        ea[ks * 2]     = __builtin_nontemporal_load((const f32x4*)&arow[ks * 32]);
        ea[ks * 2 + 1] = __builtin_nontemporal_load((const f32x4*)&arow[ks * 32 + 4]);
    }
    // ---- burst 2: 16 k/q ushort4 gathers ----
    const unsigned short* krow = &kbf[(long)er * DIN + lg * 4];
    const unsigned short* qrow = &qbf[(long)ec * DIN + lg * 4];
    ushort4 kv[8], qv[8];
#pragma unroll
    for (int ft = 0; ft < 8; ++ft) {
        kv[ft] = *(const ushort4*)&krow[ft * 16];
        qv[ft] = *(const ushort4*)&qrow[ft * 16];
    }
    __builtin_amdgcn_sched_barrier(0);   // loads stay a burst

    // convert edge_attr -> bf16 B-fragments (k-window = ks*32 + lg*8)
    short8 bfrag[4];
#pragma unroll
    for (int ks = 0; ks < 4; ++ks) {
        f32x4 a0 = ea[ks * 2], a1 = ea[ks * 2 + 1];
        short8 f;
        f[0] = (short)f2bf(a0[0]); f[1] = (short)f2bf(a0[1]);
        f[2] = (short)f2bf(a0[2]); f[3] = (short)f2bf(a0[3]);
        f[4] = (short)f2bf(a1[0]); f[5] = (short)f2bf(a1[1]);
        f[6] = (short)f2bf(a1[2]); f[7] = (short)f2bf(a1[3]);
        bfrag[ks] = f;
    }

#pragma unroll
    for (int ft = 0; ft < 8; ++ft) {             // ft == head
        f32x4 acc = (f32x4){0.f, 0.f, 0.f, 0.f};
#pragma unroll
        for (int ks = 0; ks < 4; ++ks) {
            short8 af = *(const short8*)&WEt[(ft * 16 + lr) * DIN + ks * 32 + lg * 8];
            acc = __builtin_amdgcn_mfma_f32_16x16x32_bf16(af, bfrag[ks], acc, 0, 0, 0);
        }
        const int f0 = ft * 16 + lg * 4;         // 4 consecutive features
        f32x4 t;
        t[0] = clip5(b2f(kv[ft].x) * b2f(qv[ft].x) * 0.25f) * acc[0];
        t[1] = clip5(b2f(kv[ft].y) * b2f(qv[ft].y) * 0.25f) * acc[1];
        t[2] = clip5(b2f(kv[ft].z) * b2f(qv[ft].z) * 0.25f) * acc[2];
        t[3] = clip5(b2f(kv[ft].w) * b2f(qv[ft].w) * 0.25f) * acc[3];
        __builtin_nontemporal_store(t, (f32x4*)&e_out[eg * DIN + f0]);

        float s = t[0] + t[1] + t[2] + t[3];     // this lane's 4-feature partial
        s += __shfl_xor(s, 16);                  // reduce over lg groups
        s += __shfl_xor(s, 32);
        float axv = __expf(clip5(s));
        if (lg == 0)
            ax_s[(long)j * NHEADS + ft] = axv;   // contiguous in sorted order
    }
}

// ---------------- per-node gather aggregation (no atomics) ----------------
// One wave per node. Lane = (sub = lane>>4, f16 = lane&15): each 16-lane
// group handles one edge, each lane loads 16B of v (8 bf16 features).
// 8 edges per iteration, cross-sub shfl reduce, inline normalize.

__global__ __launch_bounds__(256) void aggregate_kernel(
    const int* __restrict__ offsets, const int* __restrict__ rows_s,
    const float* __restrict__ ax_s, const unsigned short* __restrict__ vbf,
    float* __restrict__ h_out, int N) {
    int wid = blockIdx.x * 4 + (threadIdx.x >> 6);   // one wave per node
    int lane = threadIdx.x & 63;
    if (wid >= N) return;
    int beg = offsets[wid], end = offsets[wid + 1];
    const int sub = lane >> 4;       // edge within group of 4
    const int f16 = lane & 15;       // features f16*8 .. f16*8+7
    const int head = f16 >> 1;

    if (beg == end) {                // isolated node: z=0 -> h=0
        if (sub == 0) {
            f32x4 zz = (f32x4){0.f, 0.f, 0.f, 0.f};
            *(f32x4*)&h_out[(long)wid * DIN + f16 * 8] = zz;
            *(f32x4*)&h_out[(long)wid * DIN + f16 * 8 + 4] = zz;
        }
        return;
    }

    float acc[8] = {0.f, 0.f, 0.f, 0.f, 0.f, 0.f, 0.f, 0.f};
    float zacc = 0.f;

    for (int j = beg; j < end; j += 8) {
        int n = end - j;
        bool v0 = sub < n, v1 = 4 + sub < n;
        int jj0 = v0 ? (j + sub) : beg;
        int jj1 = v1 ? (j + 4 + sub) : beg;
        int r0 = rows_s[jj0], r1 = rows_s[jj1];
        float a0 = v0 ? ax_s[(long)jj0 * NHEADS + head] : 0.f;
        float a1 = v1 ? ax_s[(long)jj1 * NHEADS + head] : 0.f;
        uint4 u0 = *(const uint4*)&vbf[(long)r0 * DIN + f16 * 8];
        uint4 u1 = *(const uint4*)&vbf[(long)r1 * DIN + f16 * 8];

        acc[0] = fmaf(bflo(u0.x), a0, acc[0]); acc[1] = fmaf(bfhi(u0.x), a0, acc[1]);
        acc[2] = fmaf(bflo(u0.y), a0, acc[2]); acc[3] = fmaf(bfhi(u0.y), a0, acc[3]);
        acc[4] = fmaf(bflo(u0.z), a0, acc[4]); acc[5] = fmaf(bfhi(u0.z), a0, acc[5]);
        acc[6] = fmaf(bflo(u0.w), a0, acc[6]); acc[7] = fmaf(bfhi(u0.w), a0, acc[7]);
        zacc += a0;
        acc[0] = fmaf(bflo(u1.x), a1, acc[0]); acc[1] = fmaf(bfhi(u1.x), a1, acc[1]);
        acc[2] = fmaf(bflo(u1.y), a1, acc[2]); acc[3] = fmaf(bfhi(u1.y), a1, acc[3]);
        acc[4] = fmaf(bflo(u1.z), a1, acc[4]); acc[5] = fmaf(bfhi(u1.z), a1, acc[5]);
        acc[6] = fmaf(bflo(u1.w), a1, acc[6]); acc[7] = fmaf(bfhi(u1.w), a1, acc[7]);
        zacc += a1;
    }

#pragma unroll
    for (int i = 0; i < 8; ++i) {
        acc[i] += __shfl_xor(acc[i], 16);
        acc[i] += __shfl_xor(acc[i], 32);
    }
    zacc += __shfl_xor(zacc, 16);
    zacc += __shfl_xor(zacc, 32);

    if (sub == 0) {
        float inv = 1.0f / (zacc + 1e-6f);
        f32x4 r0 = (f32x4){acc[0] * inv, acc[1] * inv, acc[2] * inv, acc[3] * inv};
        f32x4 r1 = (f32x4){acc[4] * inv, acc[5] * inv, acc[6] * inv, acc[7] * inv};
        *(f32x4*)&h_out[(long)wid * DIN + f16 * 8] = r0;
        *(f32x4*)&h_out[(long)wid * DIN + f16 * 8 + 4] = r1;
    }
}

extern "C" void kernel_launch(void* const* d_in, const int* in_sizes, int n_in,
                              void* d_out, int out_size, void* d_ws, size_t ws_size,
                              hipStream_t stream) {
    const float* x         = (const float*)d_in[0];
    const float* edge_attr = (const float*)d_in[1];
    const int*   edge_index= (const int*)d_in[2];
    const float* WQ        = (const float*)d_in[3];
    const float* WK        = (const float*)d_in[4];
    const float* WV        = (const float*)d_in[5];
    const float* WE        = (const float*)d_in[6];

    const int N = in_sizes[0] / DIN;     // 50000
    const int E = in_sizes[2] / 2;       // 600000 (multiple of 64)
    const int NB = (N + 255) / 256;

    float* out   = (float*)d_out;
    float* h_out = out;                        // [N,128]
    float* e_out = out + (long)N * DIN;        // [E,128]

    unsigned short* qbf = (unsigned short*)d_ws;            // [N,128] bf16
    unsigned short* kbf = qbf + (long)N * DIN;              // [N,128] bf16
    unsigned short* vbf = kbf + (long)N * DIN;              // [N,128] bf16
    float* ax_s = (float*)(vbf + (long)N * DIN);            // [E,8] sorted order
    unsigned short* Wt = (unsigned short*)(ax_s + (long)E * NHEADS);  // 4x[128,128] bf16
    int* ip      = (int*)(Wt + 4 * 16384);
    int* deg     = ip;                         // [N]
    int* cursor  = deg + N;                    // [N]
    int* offsets = cursor + N;                 // [N+1]
    int* bsum    = offsets + N + 1;            // [NB]
    int* elist   = bsum + 256;                 // [E]
    int* rows_s  = elist + E;                  // [E]
    int* cols_s  = rows_s + E;                 // [E]

    const int* rows = edge_index;
    const int* cols = edge_index + E;

    hipMemsetAsync(deg, 0, (size_t)N * sizeof(int), stream);

    prep_w_kernel<<<4 * 16384 / 256, 256, 0, stream>>>(WQ, WK, WV, WE, Wt);
    node_mfma_kernel<<<(N + 63) / 64, 256, 0, stream>>>(x, Wt, qbf, kbf, vbf, N);

    degree_kernel<<<(E + 255) / 256, 256, 0, stream>>>(cols, deg, E);
    block_sum_kernel<<<NB, 256, 0, stream>>>(deg, bsum, N);
    scan_bsum_kernel<<<1, 256, 0, stream>>>(bsum, NB);
    offsets_kernel<<<NB, 256, 0, stream>>>(deg, bsum, offsets, cursor, N, E);
    scatter_kernel<<<(E + 255) / 256, 256, 0, stream>>>(rows, cols, cursor,
                                                        elist, rows_s, cols_s, E);

    edge_mfma_kernel<<<E / EPB, 256, 0, stream>>>(
        edge_attr, elist, rows_s, cols_s, Wt + 3 * 16384, qbf, kbf, e_out, ax_s, E);

    aggregate_kernel<<<(N + 3) / 4, 256, 0, stream>>>(
        offsets, rows_s, ax_s, vbf, h_out, N);
}